// Round 16
// baseline (143.025 us; speedup 1.0000x reference)
//
#include <hip/hip_runtime.h>
#include <hip/hip_fp16.h>

#define BB 8
#define CC 64
#define HH 112
#define WW 112
#define HWs (HH * WW)                 // 12544
#define KEYN 9

// ---- conv_key MFMA geometry: 128-px tile, 4 waves, 16x16x32_f16 ----
#define CKM_PX 128
#define CKM_TILES (HWs / CKM_PX)      // 98
#define CKM_NBLK (BB * CKM_TILES)     // 784
#define WTH 72                        // Wt fp16 row stride

// ---- fused sampler geometry ----
#define SM_PX 32
#define SM_TILES (HWs / SM_PX)        // 392
#define SM_NBLK (BB * SM_TILES)       // 3136

// fused-kernel LDS float offsets (phase overlays):
//   phase A (stage+conv):   Wq[64][20] @0, Sb[20] @1280, L[32][21] @1300,
//                           Xq[64][32] @1972 (end 4020)
//   phase B (softmax):      Pf float4 [288] @0 (overlays dead Wq)
//   phase C (sampling):     T2 [32px][9k][4corner]{addr,wgt} @0 (2304 f),
//                           OutT[32][68] @2304
#define OFF_WQ   0
#define OFF_SB   1280
#define OFF_L    1300
#define OFF_XQ   1972
#define OFF_P    0
#define OFF_T    0
#define OFF_OUTT 2304
#define SM_LDS   4480                 // 17.92 KB

typedef int   v4i __attribute__((ext_vector_type(4)));
typedef float v4f __attribute__((ext_vector_type(4)));
typedef _Float16 v8h __attribute__((ext_vector_type(8)));

// forced-MLP gather: result register is bound by asm -> must stay live
#define GLOAD(dst, p) asm volatile("global_load_dwordx4 %0, %1, off" \
                                   : "=&v"(dst) : "v"(p))

// xor lane swaps within 32-lane halves (BitMode: offset=(xor<<10)|0x1F)
__device__ __forceinline__ float swzx16(float v) {
    return __uint_as_float(__builtin_amdgcn_ds_swizzle(__float_as_uint(v), 0x401F));
}
__device__ __forceinline__ float swzx8(float v) {
    return __uint_as_float(__builtin_amdgcn_ds_swizzle(__float_as_uint(v), 0x201F));
}

// ---------------------------------------------------------------------------
// conv_key v3 (MFMA, R15-proven ~11us): Kf[b*HW+px][64] =
// half(W_refer @ key + b_refer) via v_mfma_f32_16x16x32_f16.
// BATCH-PINNED (b=blk&7): Kf dirty in XCD b's L2 for the pinned sampler.
// ---------------------------------------------------------------------------
__global__ __launch_bounds__(256, 4) void conv_key_kernel(
    const float* __restrict__ key, const float* __restrict__ w_refer,
    const float* __restrict__ b_refer, __half* __restrict__ Kf)
{
    __shared__ __half Wt[64 * WTH];      // 9.2 KB fp16 [o][k]

    const int t = threadIdx.x;
    const int blk = blockIdx.x;
    const int b = blk & 7;                       // batch == XCD round-robin
    const int s0 = (blk >> 3) * CKM_PX;
    const size_t inb = (size_t)b * CC * HWs + s0;

    // ---- stage Wt fp16 [o][k], rows padded to 72 halfs
    #pragma unroll
    for (int m = 0; m < 4; ++m) {
        const int f = t + 256 * m;
        const int o = f >> 4;
        const int q = f & 15;
        const float4 wv = *reinterpret_cast<const float4*>(w_refer + o * CC + 4 * q);
        __half2* dst = reinterpret_cast<__half2*>(&Wt[o * WTH + 4 * q]);
        dst[0] = __floats2half2_rn(wv.x, wv.y);
        dst[1] = __floats2half2_rn(wv.z, wv.w);
    }
    __syncthreads();

    const int l  = t & 63;
    const int w  = t >> 6;
    const int lo = l & 15;      // A-row (o) / B-col (px)
    const int hi = l >> 4;      // 0..3: k-group / D-row group
    const int px0 = w * 32;

    // ---- A fragments (weights): 4 o-tiles x 2 K-steps, ds_read_b128 each
    v8h aW[4][2];
    #pragma unroll
    for (int ot = 0; ot < 4; ++ot)
        #pragma unroll
        for (int ks = 0; ks < 2; ++ks)
            aW[ot][ks] = *reinterpret_cast<const v8h*>(
                &Wt[(ot * 16 + lo) * WTH + ks * 32 + hi * 8]);

    // ---- B fragments (key): 2 px-tiles x 2 K-steps, 8 scalar loads each
    v8h bK[2][2];
    #pragma unroll
    for (int pt = 0; pt < 2; ++pt) {
        const int px = px0 + pt * 16 + lo;
        #pragma unroll
        for (int ks = 0; ks < 2; ++ks) {
            const float* kp = key + inb + (size_t)(ks * 32 + hi * 8) * HWs + px;
            v8h bb;
            #pragma unroll
            for (int j = 0; j < 8; ++j)
                bb[j] = (_Float16)kp[(size_t)j * HWs];
            bK[pt][ks] = bb;
        }
    }

    // ---- MFMA accumulate (bias-init) + 8B fp16 stores
    #pragma unroll
    for (int ot = 0; ot < 4; ++ot) {
        const float4 bv = *reinterpret_cast<const float4*>(b_refer + ot * 16 + hi * 4);
        #pragma unroll
        for (int pt = 0; pt < 2; ++pt) {
            v4f c;
            c[0] = bv.x; c[1] = bv.y; c[2] = bv.z; c[3] = bv.w;
            c = __builtin_amdgcn_mfma_f32_16x16x32_f16(aW[ot][0], bK[pt][0], c, 0, 0, 0);
            c = __builtin_amdgcn_mfma_f32_16x16x32_f16(aW[ot][1], bK[pt][1], c, 0, 0, 0);
            const int px = px0 + pt * 16 + lo;
            const size_t ob = ((size_t)b * HWs + s0 + px) * CC + ot * 16 + hi * 4;
            union { __half2 h[2]; float2 f; } u;
            u.h[0] = __floats2half2_rn(c[0], c[1]);
            u.h[1] = __floats2half2_rn(c[2], c[3]);
            *reinterpret_cast<float2*>(Kf + ob) = u.f;   // 8B, aligned
        }
    }
}

// ---------------------------------------------------------------------------
// Bilinear data for (p,k): row bases, x0, 4 pre-multiplied corner weights.
// ---------------------------------------------------------------------------
struct TEnt { float4 a, b; };

__device__ __forceinline__ TEnt make_entry2(int e, float4 pk, int s0)
{
    const int p = e & 31;
    const int s = s0 + p;
    const int yi = s / WW;
    const int xi = s - yi * WW;
    const float py  = pk.y + (float)yi;
    const float pxf = pk.z + (float)xi;
    const float fy = floorf(py), fx = floorf(pxf);
    const float wy1 = py - fy, wx1 = pxf - fx;
    const float wy0 = 1.f - wy1, wx0 = 1.f - wx1;
    const int ix0 = (int)fx;
    const int iy0 = (int)fy, iy1 = iy0 + 1;
    const float vx0 = (ix0 >= 0 && ix0 < WW)      ? 1.f : 0.f;
    const float vx1 = (ix0 >= -1 && ix0 < WW - 1) ? 1.f : 0.f;
    const float vy0 = (iy0 >= 0 && iy0 < HH)      ? 1.f : 0.f;
    const float vy1 = (iy1 >= 0 && iy1 < HH)      ? 1.f : 0.f;
    const int yc0 = min(max(iy0, 0), HH - 1);
    const int yc1 = min(max(iy1, 0), HH - 1);
    TEnt r;
    r.a.x = __uint_as_float((unsigned)(yc0 * WW * 128));
    r.a.y = __uint_as_float((unsigned)(yc1 * WW * 128));
    r.a.z = __int_as_float(ix0);
    r.a.w = 0.f;
    const float ay0 = pk.x * wy0 * vy0;
    const float ay1 = pk.x * wy1 * vy1;
    r.b.x = ay0 * wx0 * vx0;
    r.b.y = ay0 * wx1 * vx1;
    r.b.z = ay1 * wx0 * vx0;
    r.b.w = ay1 * wx1 * vx1;
    return r;
}

// consume one 9-load cluster into OutT[p]
#define CONSUME9(twv, rrv, p) do {                                            \
    float acc_[8] = {0.f, 0.f, 0.f, 0.f, 0.f, 0.f, 0.f, 0.f};                 \
    _Pragma("unroll")                                                         \
    for (int k = 0; k < KEYN; ++k) {                                          \
        const float wgt_ = twv[k].y;                                          \
        union { int i; __half2 h; } u0_, u1_, u2_, u3_;                       \
        u0_.i = rrv[k][0]; u1_.i = rrv[k][1];                                 \
        u2_.i = rrv[k][2]; u3_.i = rrv[k][3];                                 \
        acc_[0] = fmaf(__low2float(u0_.h),  wgt_, acc_[0]);                   \
        acc_[1] = fmaf(__high2float(u0_.h), wgt_, acc_[1]);                   \
        acc_[2] = fmaf(__low2float(u1_.h),  wgt_, acc_[2]);                   \
        acc_[3] = fmaf(__high2float(u1_.h), wgt_, acc_[3]);                   \
        acc_[4] = fmaf(__low2float(u2_.h),  wgt_, acc_[4]);                   \
        acc_[5] = fmaf(__high2float(u2_.h), wgt_, acc_[5]);                   \
        acc_[6] = fmaf(__low2float(u3_.h),  wgt_, acc_[6]);                   \
        acc_[7] = fmaf(__high2float(u3_.h), wgt_, acc_[7]);                   \
    }                                                                         \
    _Pragma("unroll")                                                         \
    for (int i = 0; i < 8; ++i) acc_[i] += swzx16(acc_[i]);                   \
    _Pragma("unroll")                                                         \
    for (int i = 0; i < 8; ++i) acc_[i] += swzx8(acc_[i]);                    \
    if ((l & 24) == 0) {                                                      \
        float* d_ = OutT + (p) * 68 + ch8 * 8;                                \
        *reinterpret_cast<float4*>(d_)     =                                  \
            make_float4(acc_[0], acc_[1], acc_[2], acc_[3]);                  \
        *reinterpret_cast<float4*>(d_ + 4) =                                  \
            make_float4(acc_[4], acc_[5], acc_[6], acc_[7]);                  \
    }                                                                         \
} while (0)

// ---------------------------------------------------------------------------
// Fused: R9 drain structure WIDENED to 18-load clusters with staged
// consumption. Per jj-round: issue 9+9 loads (pixel pairs pA, pB=pA+2) ->
// vmcnt(9): consume A while B's loads remain in flight (A's ~150cy VALU
// covers B's residual latency) -> vmcnt(0): consume B. Drain stalls per
// wave drop 4 -> 2, second drain mostly pre-covered. No cross-iteration
// buffer reuse (R7's trap). launch_bounds(256,3): VGPR cap 168 holds the
// ~130-reg live set without asm-dest spill.
// ---------------------------------------------------------------------------
__global__ __launch_bounds__(256, 3) void fused_sample_kernel(
    const float* __restrict__ query, const float* __restrict__ w_attn,
    const float* __restrict__ b_attn, const float* __restrict__ w_off,
    const float* __restrict__ b_off, const __half* __restrict__ Kf,
    float* __restrict__ out)
{
    __shared__ float S[SM_LDS];
    float*  Wq   = S + OFF_WQ;     // [64][20]
    float*  Sb   = S + OFF_SB;     // [20]
    float*  L    = S + OFF_L;      // [32][21]
    float*  Xq   = S + OFF_XQ;     // [64][32]
    float4* Pf4  = reinterpret_cast<float4*>(S + OFF_P);   // [288] {a,dy,dx,-}
    float*  Tb   = S + OFF_T;      // T2: 288 (p,k) x 4 corners x {addr,wgt}
    float*  OutT = S + OFF_OUTT;   // [32][68]

    const int t = threadIdx.x;
    const int l = t & 63;
    const int w = t >> 6;
    const int blk = blockIdx.x;
    const int b = blk & 7;                       // batch == XCD round-robin
    const int tile = blk >> 3;
    const int s0 = tile * SM_PX;
    const size_t qb = (size_t)b * CC * HWs + s0;
    const char* Kfb = reinterpret_cast<const char*>(Kf) + (size_t)b * HWs * 128;

    // ---- stage transposed query weights [k][20] + biases + query tile
    for (int f = t; f < 304; f += 256) {
        const int r = f >> 4;
        const int q = f & 15;
        const float* src = (r < KEYN) ? (w_attn + r * CC) : (w_off + (r - KEYN) * CC);
        const float4 wv = *reinterpret_cast<const float4*>(src + 4 * q);
        Wq[(4 * q + 0) * 20 + r] = wv.x;
        Wq[(4 * q + 1) * 20 + r] = wv.y;
        Wq[(4 * q + 2) * 20 + r] = wv.z;
        Wq[(4 * q + 3) * 20 + r] = wv.w;
    }
    if (t < 64) Wq[t * 20 + 19] = 0.f;
    if (t < 20) Sb[t] = (t < KEYN) ? b_attn[t] : (t < 19 ? b_off[t - KEYN] : 0.f);
    #pragma unroll
    for (int m = 0; m < 2; ++m) {
        const int f = t + 256 * m;          // 0..511
        const int c = f >> 3;                // 0..63
        const int p4 = (f & 7) * 4;          // 0..28
        *reinterpret_cast<float4*>(&Xq[c * 32 + p4]) =
            *reinterpret_cast<const float4*>(query + qb + (size_t)c * HWs + p4);
    }
    __syncthreads();

    // ---- query conv: thread = (px = t&31, og = t>>5 < 5); input from LDS
    {
        const int px = t & 31;
        const int og = t >> 5;
        if (og < 5) {
            const int o4 = 4 * og;
            float4 acc = *reinterpret_cast<const float4*>(&Sb[o4]);
            #pragma unroll 8
            for (int k = 0; k < 64; ++k) {
                const float a = Xq[k * 32 + px];
                const float4 wv = *reinterpret_cast<const float4*>(&Wq[k * 20 + o4]);
                acc.x = fmaf(a, wv.x, acc.x);
                acc.y = fmaf(a, wv.y, acc.y);
                acc.z = fmaf(a, wv.z, acc.z);
                acc.w = fmaf(a, wv.w, acc.w);
            }
            L[px * 21 + o4 + 0] = acc.x;
            L[px * 21 + o4 + 1] = acc.y;
            L[px * 21 + o4 + 2] = acc.z;
            L[px * 21 + o4 + 3] = acc.w;
        }
    }
    __syncthreads();

    // ---- softmax + pack Pf[k*32+px] = {attn, dy, dx, 0} (overlays dead Wq)
    if (t < SM_PX) {
        float lg[KEYN], of[10];
        #pragma unroll
        for (int k = 0; k < KEYN; ++k) lg[k] = L[t * 21 + k];
        #pragma unroll
        for (int j = 0; j < 10; ++j) of[j] = L[t * 21 + KEYN + j];
        float m = lg[0];
        #pragma unroll
        for (int k = 1; k < KEYN; ++k) m = fmaxf(m, lg[k]);
        float s = 0.f, e[KEYN];
        #pragma unroll
        for (int k = 0; k < KEYN; ++k) { e[k] = expf(lg[k] - m); s += e[k]; }
        const float sinv = 1.0f / s;
        #pragma unroll
        for (int k = 0; k < KEYN; ++k)
            Pf4[k * 32 + t] = make_float4(e[k] * sinv, of[k], of[k + 1], 0.f);
    }
    __syncthreads();

    // ---- build T2: entry e = k*32+p -> 4 corner records at float index
    // (p*9+k)*8 + corner*2: {addr = rowbase + clamp(x0+c2)*128, wgt}.
    {
        const float4 q1 = Pf4[t];
        float4 q2 = make_float4(0.f, 0.f, 0.f, 0.f);
        if (t < 32) q2 = Pf4[256 + t];
        __syncthreads();
        #pragma unroll
        for (int m = 0; m < 2; ++m) {
            const int e = (m == 0) ? t : (256 + t);
            if (m == 1 && t >= 32) break;
            const TEnt en = make_entry2(e, (m == 0) ? q1 : q2, s0);
            const int p = e & 31, k = e >> 5;
            const int x0 = __float_as_int(en.a.z);
            const unsigned xc0 = (unsigned)(min(max(x0, 0), WW - 1)) << 7;
            const unsigned xc1 = (unsigned)(min(max(x0 + 1, 0), WW - 1)) << 7;
            const unsigned rb0 = __float_as_uint(en.a.x);
            const unsigned rb1 = __float_as_uint(en.a.y);
            float4 r0, r1;
            r0.x = __uint_as_float(rb0 + xc0); r0.y = en.b.x;   // (y0,x0)
            r0.z = __uint_as_float(rb0 + xc1); r0.w = en.b.y;   // (y0,x1)
            r1.x = __uint_as_float(rb1 + xc0); r1.y = en.b.z;   // (y1,x0)
            r1.z = __uint_as_float(rb1 + xc1); r1.w = en.b.w;   // (y1,x1)
            float* dst = Tb + (p * 9 + k) * 8;
            *reinterpret_cast<float4*>(dst)     = r0;
            *reinterpret_cast<float4*>(dst + 4) = r1;
        }
    }
    __syncthreads();

    // ---- sampling: wave w -> px [8w,8w+8) as 2 WIDE rounds (2 pixel
    // pairs each). Lane = (sub=l>>5 pixel, corner=(l>>3)&3, ch8=l&7).
    const int  ch8  = l & 7;                  // 8-channel chunk
    const int  corf = ((l >> 3) & 3) * 2;     // corner float offset in T2
    const int  sub  = l >> 5;                 // which pixel of the pair
    const char* KfbC = Kfb + (unsigned)(ch8 * 16);

    #pragma unroll
    for (int jj = 0; jj < 2; ++jj) {
        const int pA = w * 8 + 4 * jj + sub;
        const int pB = pA + 2;
        const float* TeA = Tb + pA * 72 + corf;
        const float* TeB = Tb + pB * 72 + corf;

        // 18 broadcast b64 table reads
        float2 twA[KEYN], twB[KEYN];
        #pragma unroll
        for (int k = 0; k < KEYN; ++k) {
            twA[k] = *reinterpret_cast<const float2*>(TeA + k * 8);
            twB[k] = *reinterpret_cast<const float2*>(TeB + k * 8);
        }

        // 18 forced-cluster gathers; distinct named buffers (no reuse)
        v4i rrA[KEYN], rrB[KEYN];
        #pragma unroll
        for (int k = 0; k < KEYN; ++k)
            GLOAD(rrA[k], KfbC + __float_as_uint(twA[k].x));
        #pragma unroll
        for (int k = 0; k < KEYN; ++k)
            GLOAD(rrB[k], KfbC + __float_as_uint(twB[k].x));

        // staged consumption: A at vmcnt(9) (B stays in flight), B at 0
        asm volatile("s_waitcnt vmcnt(9)" ::: "memory");
        __builtin_amdgcn_sched_barrier(0);
        CONSUME9(twA, rrA, pA);
        asm volatile("s_waitcnt vmcnt(0)" ::: "memory");
        __builtin_amdgcn_sched_barrier(0);
        CONSUME9(twB, rrB, pB);
    }
    __syncthreads();

    // ---- transposed store: out[b][c][s0+px]
    const size_t ob = (size_t)b * CC * HWs + s0;
    #pragma unroll
    for (int m = 0; m < 8; ++m) {
        const int f = t + 256 * m;
        const int c = f >> 5;
        const int px = f & 31;
        out[ob + (size_t)c * HWs + px] = OutT[px * 68 + c];
    }
}

extern "C" void kernel_launch(void* const* d_in, const int* in_sizes, int n_in,
                              void* d_out, int out_size, void* d_ws, size_t ws_size,
                              hipStream_t stream)
{
    const float* query   = (const float*)d_in[0];
    const float* key     = (const float*)d_in[1];
    const float* w_refer = (const float*)d_in[2];
    const float* b_refer = (const float*)d_in[3];
    const float* w_attn  = (const float*)d_in[4];
    const float* b_attn  = (const float*)d_in[5];
    const float* w_off   = (const float*)d_in[6];
    const float* b_off   = (const float*)d_in[7];
    float* out = (float*)d_out;

    __half* Kf = (__half*)d_ws;   // [B*HW][64] pixel-major fp16, 12.8 MB

    hipLaunchKernelGGL(conv_key_kernel, dim3(CKM_NBLK), dim3(256), 0, stream,
                       key, w_refer, b_refer, Kf);
    hipLaunchKernelGGL(fused_sample_kernel, dim3(SM_NBLK), dim3(256), 0, stream,
                       query, w_attn, b_attn, w_off, b_off, Kf, out);
}

// Round 18
// 137.018 us; speedup vs baseline: 1.0438x; 1.0438x over previous
//
#include <hip/hip_runtime.h>
#include <hip/hip_fp16.h>

#define BB 8
#define CC 64
#define HH 112
#define WW 112
#define HWs (HH * WW)                 // 12544
#define KEYN 9

// ---- conv_key MFMA geometry: 128-px tile, 4 waves, 16x16x32_f16 ----
#define CKM_PX 128
#define CKM_TILES (HWs / CKM_PX)      // 98
#define CKM_NBLK (BB * CKM_TILES)     // 784
#define WTH 72                        // Wt fp16 row stride

// ---- fused sampler geometry (R9/R15-proven, fused = 42.0-42.4 us) ----
#define SM_PX 32
#define SM_TILES (HWs / SM_PX)        // 392
#define SM_NBLK (BB * SM_TILES)       // 3136

// fused-kernel LDS float offsets (phase overlays):
//   phase A (stage+conv):   Wq[64][20] @0, Sb[20] @1280, L[32][21] @1300,
//                           Xq[64][32] @1972 (end 4020)
//   phase B (softmax):      Pf float4 [288] @0 (overlays dead Wq)
//   phase C (sampling):     T2 [32px][9k][4corner]{addr,wgt} @0 (2304 f),
//                           OutT[32][68] @2304
#define OFF_WQ   0
#define OFF_SB   1280
#define OFF_L    1300
#define OFF_XQ   1972
#define OFF_P    0
#define OFF_T    0
#define OFF_OUTT 2304
#define SM_LDS   4480                 // 17.92 KB

typedef int   v4i __attribute__((ext_vector_type(4)));
typedef float v4f __attribute__((ext_vector_type(4)));
typedef _Float16 v8h __attribute__((ext_vector_type(8)));

// forced-MLP gather: result register is bound by asm -> must stay live
#define GLOAD(dst, p) asm volatile("global_load_dwordx4 %0, %1, off" \
                                   : "=&v"(dst) : "v"(p))

// xor lane swaps within 32-lane halves (BitMode: offset=(xor<<10)|0x1F)
__device__ __forceinline__ float swzx16(float v) {
    return __uint_as_float(__builtin_amdgcn_ds_swizzle(__float_as_uint(v), 0x401F));
}
__device__ __forceinline__ float swzx8(float v) {
    return __uint_as_float(__builtin_amdgcn_ds_swizzle(__float_as_uint(v), 0x201F));
}

// ---------------------------------------------------------------------------
// conv_key v3 (MFMA, R15-proven ~11us): Kf[b*HW+px][64] =
// half(W_refer @ key + b_refer) via v_mfma_f32_16x16x32_f16.
//   A = W fragment: row=o=(l&15), k=(l>>4)*8+j (16B ds_read_b128 from
//       fp16 Wt[o][k], 72-half padded rows).
//   B = key fragment: col=px=(l&15), k strided scalar loads + cvt.
//   D lane layout: px=(l&15), o=(l>>4)*4+reg -> 8B fp16 store.
// BATCH-PINNED (b=blk&7): Kf dirty in XCD b's L2 for the pinned sampler
// (R6/R8/R9 quantified: pin = -9.5us sampler, best net config).
// ---------------------------------------------------------------------------
__global__ __launch_bounds__(256, 4) void conv_key_kernel(
    const float* __restrict__ key, const float* __restrict__ w_refer,
    const float* __restrict__ b_refer, __half* __restrict__ Kf)
{
    __shared__ __half Wt[64 * WTH];      // 9.2 KB fp16 [o][k]

    const int t = threadIdx.x;
    const int blk = blockIdx.x;
    const int b = blk & 7;                       // batch == XCD round-robin
    const int s0 = (blk >> 3) * CKM_PX;
    const size_t inb = (size_t)b * CC * HWs + s0;

    // ---- stage Wt fp16 [o][k], rows padded to 72 halfs
    #pragma unroll
    for (int m = 0; m < 4; ++m) {
        const int f = t + 256 * m;
        const int o = f >> 4;
        const int q = f & 15;
        const float4 wv = *reinterpret_cast<const float4*>(w_refer + o * CC + 4 * q);
        __half2* dst = reinterpret_cast<__half2*>(&Wt[o * WTH + 4 * q]);
        dst[0] = __floats2half2_rn(wv.x, wv.y);
        dst[1] = __floats2half2_rn(wv.z, wv.w);
    }
    __syncthreads();

    const int l  = t & 63;
    const int w  = t >> 6;
    const int lo = l & 15;      // A-row (o) / B-col (px)
    const int hi = l >> 4;      // 0..3: k-group / D-row group
    const int px0 = w * 32;

    // ---- A fragments (weights): 4 o-tiles x 2 K-steps, ds_read_b128 each
    v8h aW[4][2];
    #pragma unroll
    for (int ot = 0; ot < 4; ++ot)
        #pragma unroll
        for (int ks = 0; ks < 2; ++ks)
            aW[ot][ks] = *reinterpret_cast<const v8h*>(
                &Wt[(ot * 16 + lo) * WTH + ks * 32 + hi * 8]);

    // ---- B fragments (key): 2 px-tiles x 2 K-steps, 8 scalar loads each
    v8h bK[2][2];
    #pragma unroll
    for (int pt = 0; pt < 2; ++pt) {
        const int px = px0 + pt * 16 + lo;
        #pragma unroll
        for (int ks = 0; ks < 2; ++ks) {
            const float* kp = key + inb + (size_t)(ks * 32 + hi * 8) * HWs + px;
            v8h bb;
            #pragma unroll
            for (int j = 0; j < 8; ++j)
                bb[j] = (_Float16)kp[(size_t)j * HWs];
            bK[pt][ks] = bb;
        }
    }

    // ---- MFMA accumulate (bias-init) + 8B fp16 stores
    #pragma unroll
    for (int ot = 0; ot < 4; ++ot) {
        const float4 bv = *reinterpret_cast<const float4*>(b_refer + ot * 16 + hi * 4);
        #pragma unroll
        for (int pt = 0; pt < 2; ++pt) {
            v4f c;
            c[0] = bv.x; c[1] = bv.y; c[2] = bv.z; c[3] = bv.w;
            c = __builtin_amdgcn_mfma_f32_16x16x32_f16(aW[ot][0], bK[pt][0], c, 0, 0, 0);
            c = __builtin_amdgcn_mfma_f32_16x16x32_f16(aW[ot][1], bK[pt][1], c, 0, 0, 0);
            const int px = px0 + pt * 16 + lo;
            const size_t ob = ((size_t)b * HWs + s0 + px) * CC + ot * 16 + hi * 4;
            union { __half2 h[2]; float2 f; } u;
            u.h[0] = __floats2half2_rn(c[0], c[1]);
            u.h[1] = __floats2half2_rn(c[2], c[3]);
            *reinterpret_cast<float2*>(Kf + ob) = u.f;   // 8B, aligned
        }
    }
}

// ---------------------------------------------------------------------------
// Bilinear data for (p,k): row bases, x0, 4 pre-multiplied corner weights.
// ---------------------------------------------------------------------------
struct TEnt { float4 a, b; };

__device__ __forceinline__ TEnt make_entry2(int e, float4 pk, int s0)
{
    const int p = e & 31;
    const int s = s0 + p;
    const int yi = s / WW;
    const int xi = s - yi * WW;
    const float py  = pk.y + (float)yi;
    const float pxf = pk.z + (float)xi;
    const float fy = floorf(py), fx = floorf(pxf);
    const float wy1 = py - fy, wx1 = pxf - fx;
    const float wy0 = 1.f - wy1, wx0 = 1.f - wx1;
    const int ix0 = (int)fx;
    const int iy0 = (int)fy, iy1 = iy0 + 1;
    const float vx0 = (ix0 >= 0 && ix0 < WW)      ? 1.f : 0.f;
    const float vx1 = (ix0 >= -1 && ix0 < WW - 1) ? 1.f : 0.f;
    const float vy0 = (iy0 >= 0 && iy0 < HH)      ? 1.f : 0.f;
    const float vy1 = (iy1 >= 0 && iy1 < HH)      ? 1.f : 0.f;
    const int yc0 = min(max(iy0, 0), HH - 1);
    const int yc1 = min(max(iy1, 0), HH - 1);
    TEnt r;
    r.a.x = __uint_as_float((unsigned)(yc0 * WW * 128));
    r.a.y = __uint_as_float((unsigned)(yc1 * WW * 128));
    r.a.z = __int_as_float(ix0);
    r.a.w = 0.f;
    const float ay0 = pk.x * wy0 * vy0;
    const float ay1 = pk.x * wy1 * vy1;
    r.b.x = ay0 * wx0 * vx0;
    r.b.y = ay0 * wx1 * vx1;
    r.b.z = ay1 * wx0 * vx0;
    r.b.w = ay1 * wx1 * vx1;
    return r;
}

// ---------------------------------------------------------------------------
// Fused (R9-proven drain structure, frozen after 8 structural variants all
// landed 42+-1.5 us or worse): query conv -> softmax -> pre-selected
// corner table T2[p][k][corner] = {addr, wgt} -> 9-deep forced gather
// cluster per round (asm loads, vmcnt(0), fence, consume). The sampler is
// TA/L2-issue-rate bound; hipcc's RA caps per-wave asm-load MLP at ~9, so
// TLP at (256,4) is the operating point.
// ---------------------------------------------------------------------------
__global__ __launch_bounds__(256, 4) void fused_sample_kernel(
    const float* __restrict__ query, const float* __restrict__ w_attn,
    const float* __restrict__ b_attn, const float* __restrict__ w_off,
    const float* __restrict__ b_off, const __half* __restrict__ Kf,
    float* __restrict__ out)
{
    __shared__ float S[SM_LDS];
    float*  Wq   = S + OFF_WQ;     // [64][20]
    float*  Sb   = S + OFF_SB;     // [20]
    float*  L    = S + OFF_L;      // [32][21]
    float*  Xq   = S + OFF_XQ;     // [64][32]
    float4* Pf4  = reinterpret_cast<float4*>(S + OFF_P);   // [288] {a,dy,dx,-}
    float*  Tb   = S + OFF_T;      // T2: 288 (p,k) x 4 corners x {addr,wgt}
    float*  OutT = S + OFF_OUTT;   // [32][68]

    const int t = threadIdx.x;
    const int l = t & 63;
    const int w = t >> 6;
    const int blk = blockIdx.x;
    const int b = blk & 7;                       // batch == XCD round-robin
    const int tile = blk >> 3;
    const int s0 = tile * SM_PX;
    const size_t qb = (size_t)b * CC * HWs + s0;
    const char* Kfb = reinterpret_cast<const char*>(Kf) + (size_t)b * HWs * 128;

    // ---- stage transposed query weights [k][20] + biases + query tile
    for (int f = t; f < 304; f += 256) {
        const int r = f >> 4;
        const int q = f & 15;
        const float* src = (r < KEYN) ? (w_attn + r * CC) : (w_off + (r - KEYN) * CC);
        const float4 wv = *reinterpret_cast<const float4*>(src + 4 * q);
        Wq[(4 * q + 0) * 20 + r] = wv.x;
        Wq[(4 * q + 1) * 20 + r] = wv.y;
        Wq[(4 * q + 2) * 20 + r] = wv.z;
        Wq[(4 * q + 3) * 20 + r] = wv.w;
    }
    if (t < 64) Wq[t * 20 + 19] = 0.f;
    if (t < 20) Sb[t] = (t < KEYN) ? b_attn[t] : (t < 19 ? b_off[t - KEYN] : 0.f);
    #pragma unroll
    for (int m = 0; m < 2; ++m) {
        const int f = t + 256 * m;          // 0..511
        const int c = f >> 3;                // 0..63
        const int p4 = (f & 7) * 4;          // 0..28
        *reinterpret_cast<float4*>(&Xq[c * 32 + p4]) =
            *reinterpret_cast<const float4*>(query + qb + (size_t)c * HWs + p4);
    }
    __syncthreads();

    // ---- query conv: thread = (px = t&31, og = t>>5 < 5); input from LDS
    {
        const int px = t & 31;
        const int og = t >> 5;
        if (og < 5) {
            const int o4 = 4 * og;
            float4 acc = *reinterpret_cast<const float4*>(&Sb[o4]);
            #pragma unroll 8
            for (int k = 0; k < 64; ++k) {
                const float a = Xq[k * 32 + px];
                const float4 wv = *reinterpret_cast<const float4*>(&Wq[k * 20 + o4]);
                acc.x = fmaf(a, wv.x, acc.x);
                acc.y = fmaf(a, wv.y, acc.y);
                acc.z = fmaf(a, wv.z, acc.z);
                acc.w = fmaf(a, wv.w, acc.w);
            }
            L[px * 21 + o4 + 0] = acc.x;
            L[px * 21 + o4 + 1] = acc.y;
            L[px * 21 + o4 + 2] = acc.z;
            L[px * 21 + o4 + 3] = acc.w;
        }
    }
    __syncthreads();

    // ---- softmax + pack Pf[k*32+px] = {attn, dy, dx, 0} (overlays dead Wq)
    if (t < SM_PX) {
        float lg[KEYN], of[10];
        #pragma unroll
        for (int k = 0; k < KEYN; ++k) lg[k] = L[t * 21 + k];
        #pragma unroll
        for (int j = 0; j < 10; ++j) of[j] = L[t * 21 + KEYN + j];
        float m = lg[0];
        #pragma unroll
        for (int k = 1; k < KEYN; ++k) m = fmaxf(m, lg[k]);
        float s = 0.f, e[KEYN];
        #pragma unroll
        for (int k = 0; k < KEYN; ++k) { e[k] = expf(lg[k] - m); s += e[k]; }
        const float sinv = 1.0f / s;
        #pragma unroll
        for (int k = 0; k < KEYN; ++k)
            Pf4[k * 32 + t] = make_float4(e[k] * sinv, of[k], of[k + 1], 0.f);
    }
    __syncthreads();

    // ---- build T2: entry e = k*32+p -> 4 corner records at float index
    // (p*9+k)*8 + corner*2: {addr = rowbase + clamp(x0+c2)*128, wgt}.
    {
        const float4 q1 = Pf4[t];
        float4 q2 = make_float4(0.f, 0.f, 0.f, 0.f);
        if (t < 32) q2 = Pf4[256 + t];
        __syncthreads();
        #pragma unroll
        for (int m = 0; m < 2; ++m) {
            const int e = (m == 0) ? t : (256 + t);
            if (m == 1 && t >= 32) break;
            const TEnt en = make_entry2(e, (m == 0) ? q1 : q2, s0);
            const int p = e & 31, k = e >> 5;
            const int x0 = __float_as_int(en.a.z);
            const unsigned xc0 = (unsigned)(min(max(x0, 0), WW - 1)) << 7;
            const unsigned xc1 = (unsigned)(min(max(x0 + 1, 0), WW - 1)) << 7;
            const unsigned rb0 = __float_as_uint(en.a.x);
            const unsigned rb1 = __float_as_uint(en.a.y);
            float4 r0, r1;
            r0.x = __uint_as_float(rb0 + xc0); r0.y = en.b.x;   // (y0,x0)
            r0.z = __uint_as_float(rb0 + xc1); r0.w = en.b.y;   // (y0,x1)
            r1.x = __uint_as_float(rb1 + xc0); r1.y = en.b.z;   // (y1,x0)
            r1.z = __uint_as_float(rb1 + xc1); r1.w = en.b.w;   // (y1,x1)
            float* dst = Tb + (p * 9 + k) * 8;
            *reinterpret_cast<float4*>(dst)     = r0;
            *reinterpret_cast<float4*>(dst + 4) = r1;
        }
    }
    __syncthreads();

    // ---- sampling: wave w -> px [8w,8w+8) as 4 rounds of a pixel pair.
    // Lane = (sub=l>>5 pixel, corner=(l>>3)&3, ch8=l&7).
    const int  ch8  = l & 7;                  // 8-channel chunk
    const int  corf = ((l >> 3) & 3) * 2;     // corner float offset in T2
    const int  sub  = l >> 5;                 // which pixel of the pair
    const char* KfbC = Kfb + (unsigned)(ch8 * 16);

    for (int j = 0; j < 4; ++j) {
        const int p = w * 8 + 2 * j + sub;
        const float* Te = Tb + p * 72 + corf;     // + k*8 per key

        // 9 broadcast b64 reads: {addr, wgt} per (p,k,corner)
        float2 tw[KEYN];
        #pragma unroll
        for (int k = 0; k < KEYN; ++k)
            tw[k] = *reinterpret_cast<const float2*>(Te + k * 8);

        // 9 forced-cluster gathers (16B each); all dests live at the wait
        v4i rr[KEYN];
        #pragma unroll
        for (int k = 0; k < KEYN; ++k)
            GLOAD(rr[k], KfbC + __float_as_uint(tw[k].x));
        asm volatile("s_waitcnt vmcnt(0)" ::: "memory");
        __builtin_amdgcn_sched_barrier(0);

        float acc[8] = {0.f, 0.f, 0.f, 0.f, 0.f, 0.f, 0.f, 0.f};
        #pragma unroll
        for (int k = 0; k < KEYN; ++k) {
            const float wgt = tw[k].y;
            union { int i; __half2 h; } u0, u1, u2, u3;
            u0.i = rr[k][0]; u1.i = rr[k][1]; u2.i = rr[k][2]; u3.i = rr[k][3];
            acc[0] = fmaf(__low2float(u0.h),  wgt, acc[0]);
            acc[1] = fmaf(__high2float(u0.h), wgt, acc[1]);
            acc[2] = fmaf(__low2float(u1.h),  wgt, acc[2]);
            acc[3] = fmaf(__high2float(u1.h), wgt, acc[3]);
            acc[4] = fmaf(__low2float(u2.h),  wgt, acc[4]);
            acc[5] = fmaf(__high2float(u2.h), wgt, acc[5]);
            acc[6] = fmaf(__low2float(u3.h),  wgt, acc[6]);
            acc[7] = fmaf(__high2float(u3.h), wgt, acc[7]);
        }

        // fold y-corner pairs (lane^16), then x-corner pairs (lane^8)
        #pragma unroll
        for (int i = 0; i < 8; ++i) acc[i] += swzx16(acc[i]);
        #pragma unroll
        for (int i = 0; i < 8; ++i) acc[i] += swzx8(acc[i]);

        if ((l & 24) == 0) {
            float* d = OutT + p * 68 + ch8 * 8;
            *reinterpret_cast<float4*>(d)     = make_float4(acc[0], acc[1], acc[2], acc[3]);
            *reinterpret_cast<float4*>(d + 4) = make_float4(acc[4], acc[5], acc[6], acc[7]);
        }
    }
    __syncthreads();

    // ---- transposed store: out[b][c][s0+px]
    const size_t ob = (size_t)b * CC * HWs + s0;
    #pragma unroll
    for (int m = 0; m < 8; ++m) {
        const int f = t + 256 * m;
        const int c = f >> 5;
        const int px = f & 31;
        out[ob + (size_t)c * HWs + px] = OutT[px * 68 + c];
    }
}

extern "C" void kernel_launch(void* const* d_in, const int* in_sizes, int n_in,
                              void* d_out, int out_size, void* d_ws, size_t ws_size,
                              hipStream_t stream)
{
    const float* query   = (const float*)d_in[0];
    const float* key     = (const float*)d_in[1];
    const float* w_refer = (const float*)d_in[2];
    const float* b_refer = (const float*)d_in[3];
    const float* w_attn  = (const float*)d_in[4];
    const float* b_attn  = (const float*)d_in[5];
    const float* w_off   = (const float*)d_in[6];
    const float* b_off   = (const float*)d_in[7];
    float* out = (float*)d_out;

    __half* Kf = (__half*)d_ws;   // [B*HW][64] pixel-major fp16, 12.8 MB

    hipLaunchKernelGGL(conv_key_kernel, dim3(CKM_NBLK), dim3(256), 0, stream,
                       key, w_refer, b_refer, Kf);
    hipLaunchKernelGGL(fused_sample_kernel, dim3(SM_NBLK), dim3(256), 0, stream,
                       query, w_attn, b_attn, w_off, b_off, Kf, out);
}